// Round 4
// baseline (549.219 us; speedup 1.0000x reference)
//
#include <hip/hip_runtime.h>

#define NN 50000
#define NE 800000
#define NG 128
#define NC 41
#define CAP 64

typedef __attribute__((ext_vector_type(8))) short bfrag8;
typedef __attribute__((ext_vector_type(4))) float facc4;

__device__ __forceinline__ float bf2f(unsigned short u) {
  union { unsigned int i; float f; } v; v.i = ((unsigned int)u) << 16; return v.f;
}
__device__ __forceinline__ unsigned short f2bf(float f) {
  union { float f; unsigned int i; } v; v.f = f;
  unsigned int x = v.i;
  x += 0x7fffu + ((x >> 16) & 1u);
  return (unsigned short)(x >> 16);
}
__device__ __forceinline__ void acc_u4(const uint4 u, float* a) {
  union { unsigned int i; float f; } c;
  c.i = u.x << 16;          a[0] += c.f;
  c.i = u.x & 0xffff0000u;  a[1] += c.f;
  c.i = u.y << 16;          a[2] += c.f;
  c.i = u.y & 0xffff0000u;  a[3] += c.f;
  c.i = u.z << 16;          a[4] += c.f;
  c.i = u.z & 0xffff0000u;  a[5] += c.f;
  c.i = u.w << 16;          a[6] += c.f;
  c.i = u.w & 0xffff0000u;  a[7] += c.f;
}
__device__ __forceinline__ unsigned int pack2(float lo, float hi) {
  return (unsigned int)f2bf(lo) | ((unsigned int)f2bf(hi) << 16);
}

// Fused: embed (blocks [0,6250)), fill (blocks [6250,9375)), prep (blocks [9375,9439)).
// All three write disjoint outputs; no inter-part dependency.
__global__ void pre_kernel(const int* __restrict__ node_ids, const float* __restrict__ emb,
                           unsigned short* __restrict__ xb,
                           const int* __restrict__ ei, int* __restrict__ cnt,
                           int* __restrict__ srclist,
                           const float* __restrict__ W1, const float* __restrict__ W2,
                           const float* __restrict__ oW1, const float* __restrict__ oW2,
                           const float* __restrict__ gamma, const float* __restrict__ beta,
                           const float* __restrict__ mean, const float* __restrict__ var,
                           unsigned short* W1b, unsigned short* W2b,
                           unsigned short* oW1b, unsigned short* oW2b,
                           float* scale, float* shift) {
  int bid = blockIdx.x;
  if (bid < 6250) {              // embed: one thread per 4 feats
    int idx = bid * 256 + threadIdx.x;
    if (idx >= NN * 32) return;
    int node = idx >> 5, f = (idx & 31) * 4;
    const float4 v = *(const float4*)&emb[node_ids[node] * 128 + f];
    ushort4 o;
    o.x = f2bf(v.x); o.y = f2bf(v.y); o.z = f2bf(v.z); o.w = f2bf(v.w);
    *(ushort4*)&xb[node * 128 + f] = o;
  } else if (bid < 9375) {       // fill: bucket edges by dst
    int e = (bid - 6250) * 256 + threadIdx.x;
    if (e >= NE) return;
    int s = ei[e];
    int d = ei[NE + e];
    int pos = atomicAdd(&cnt[d], 1);
    if (pos < CAP) srclist[d * CAP + pos] = s;
  } else {                       // prep: weights->bf16, BN affine
    int i = (bid - 9375) * 256 + threadIdx.x;
    if (i < 128 * 128) {
      W1b[i] = f2bf(W1[i]);
      W2b[i] = f2bf(W2[i]);
      oW1b[i] = f2bf(oW1[i]);
      oW2b[i] = f2bf(oW2[i]);
    }
    if (i < 128) {
      float s = gamma[i] * rsqrtf(var[i] + 1e-5f);
      scale[i] = s;
      shift[i] = beta[i] - mean[i] * s;
    }
  }
}

// h = x + sum_{neighbors} x. 16 nodes/block, 16 lanes/node, 16B loads, unroll 4.
// (round-2 proven)
__global__ __launch_bounds__(256) void agg_kernel(const unsigned short* __restrict__ xb,
                                                  const int* __restrict__ cnt,
                                                  const int* __restrict__ srclist,
                                                  unsigned short* __restrict__ hb) {
  int tid = threadIdx.x;
  int node = blockIdx.x * 16 + (tid >> 4);
  if (node >= NN) return;
  int f = (tid & 15) * 8;
  float a[8];
  acc_u4(*(const uint4*)&xb[node * 128 + f],
         (a[0]=0.f, a[1]=0.f, a[2]=0.f, a[3]=0.f, a[4]=0.f, a[5]=0.f, a[6]=0.f, a[7]=0.f, a));
  int deg = cnt[node];
  if (deg > CAP) deg = CAP;
  const int* lst = &srclist[node * CAP];
  int j = 0;
  for (; j + 4 <= deg; j += 4) {
    int n0 = lst[j], n1 = lst[j + 1], n2 = lst[j + 2], n3 = lst[j + 3];
    uint4 u0 = *(const uint4*)&xb[n0 * 128 + f];
    uint4 u1 = *(const uint4*)&xb[n1 * 128 + f];
    uint4 u2 = *(const uint4*)&xb[n2 * 128 + f];
    uint4 u3 = *(const uint4*)&xb[n3 * 128 + f];
    acc_u4(u0, a); acc_u4(u1, a); acc_u4(u2, a); acc_u4(u3, a);
  }
  for (; j < deg; ++j) {
    uint4 u = *(const uint4*)&xb[lst[j] * 128 + f];
    acc_u4(u, a);
  }
  uint4 o;
  o.x = pack2(a[0], a[1]); o.y = pack2(a[2], a[3]);
  o.z = pack2(a[4], a[5]); o.w = pack2(a[6], a[7]);
  *(uint4*)&hb[node * 128 + f] = o;
}

// Fused MLP: Out = ep2(relu(A@W1^T+b1) @ W2^T + b2) for a 64-row tile.
// (round-2 proven: barriers between all LDS producer/consumer phases)
__global__ __launch_bounds__(256) void mlp_kernel(const unsigned short* __restrict__ A,
                                                  const unsigned short* __restrict__ W1b,
                                                  const unsigned short* __restrict__ W2b,
                                                  const float* __restrict__ bias1,
                                                  const float* __restrict__ bias2,
                                                  const float* __restrict__ scale,
                                                  const float* __restrict__ shift,
                                                  unsigned short* __restrict__ Out,
                                                  int M, int mode) {
  __shared__ unsigned short sW1[128][136];
  __shared__ unsigned short sW2[128][136];
  __shared__ unsigned short sA[64][136];
  __shared__ unsigned short sT[64][136];
  int tid = threadIdx.x;
  int bRow = blockIdx.x * 64;

  const uint4* gw1 = (const uint4*)W1b;
  const uint4* gw2 = (const uint4*)W2b;
#pragma unroll
  for (int p = 0; p < 8; ++p) {
    int idx = (p * 256 + tid) * 8;
    int r = idx >> 7, c = idx & 127;
    *(uint4*)&sW1[r][c] = gw1[p * 256 + tid];
    *(uint4*)&sW2[r][c] = gw2[p * 256 + tid];
  }
#pragma unroll
  for (int p = 0; p < 4; ++p) {
    int idx = (p * 256 + tid) * 8;
    int r = idx >> 7, c = idx & 127;
    int grow = bRow + r;
    uint4 v = {0u, 0u, 0u, 0u};
    if (grow < M) v = *(const uint4*)&A[grow * 128 + c];
    *(uint4*)&sA[r][c] = v;
  }
  __syncthreads();

  int wave = tid >> 6;
  int lane = tid & 63;
  int l16 = lane & 15;
  int quad = lane >> 4;
  int arow = wave * 16 + l16;

  // ---- GEMM1: T = relu(A @ W1^T + b1) ----
  {
    facc4 acc[8];
#pragma unroll
    for (int t = 0; t < 8; ++t) acc[t] = (facc4){0.f, 0.f, 0.f, 0.f};
#pragma unroll
    for (int k = 0; k < 4; ++k) {
      bfrag8 af = *(const bfrag8*)&sA[arow][k * 32 + quad * 8];
#pragma unroll
      for (int t = 0; t < 8; ++t) {
        bfrag8 bf = *(const bfrag8*)&sW1[t * 16 + l16][k * 32 + quad * 8];
        acc[t] = __builtin_amdgcn_mfma_f32_16x16x32_bf16(af, bf, acc[t], 0, 0, 0);
      }
    }
#pragma unroll
    for (int t = 0; t < 8; ++t) {
      int col = t * 16 + l16;
      float b = bias1[col];
#pragma unroll
      for (int i = 0; i < 4; ++i) {
        int row = wave * 16 + quad * 4 + i;
        float v = acc[t][i] + b;
        sT[row][col] = f2bf(v > 0.f ? v : 0.f);
      }
    }
  }
  __syncthreads();

  // ---- GEMM2: Out = ep2(T @ W2^T + b2) ----
  {
    facc4 acc[8];
#pragma unroll
    for (int t = 0; t < 8; ++t) acc[t] = (facc4){0.f, 0.f, 0.f, 0.f};
#pragma unroll
    for (int k = 0; k < 4; ++k) {
      bfrag8 af = *(const bfrag8*)&sT[arow][k * 32 + quad * 8];
#pragma unroll
      for (int t = 0; t < 8; ++t) {
        bfrag8 bf = *(const bfrag8*)&sW2[t * 16 + l16][k * 32 + quad * 8];
        acc[t] = __builtin_amdgcn_mfma_f32_16x16x32_bf16(af, bf, acc[t], 0, 0, 0);
      }
    }
#pragma unroll
    for (int t = 0; t < 8; ++t) {
      int col = t * 16 + l16;
      float b = bias2[col];
      float sc = 1.f, sh = 0.f;
      if (mode == 1) { sc = scale[col]; sh = shift[col]; }
#pragma unroll
      for (int i = 0; i < 4; ++i) {
        int row = wave * 16 + quad * 4 + i;
        float v = acc[t][i] + b;
        v = v > 0.f ? v : 0.f;
        if (mode == 1) v = v * sc + sh;
        sA[row][col] = f2bf(v);
      }
    }
  }
  __syncthreads();

#pragma unroll
  for (int p = 0; p < 4; ++p) {
    int idx = (p * 256 + tid) * 8;
    int r = idx >> 7, c = idx & 127;
    int grow = bRow + r;
    if (grow < M) *(uint4*)&Out[grow * 128 + c] = *(const uint4*)&sA[r][c];
  }
}

// pooled[g, f] += sum over contiguous nodes with batch==g (batch sorted)
__global__ __launch_bounds__(128) void pool_kernel(const unsigned short* __restrict__ xb,
                                                   const int* __restrict__ batch,
                                                   float* __restrict__ pooled) {
  const int CHUNK = 128;
  int start = blockIdx.x * CHUNK;
  int end = start + CHUNK;
  if (end > NN) end = NN;
  int f = threadIdx.x;
  float acc = 0.f;
  int cur = -1;
  for (int i = start; i < end; ++i) {
    int b = batch[i];
    if (b != cur) {
      if (cur >= 0) atomicAdd(&pooled[cur * 128 + f], acc);
      cur = b;
      acc = 0.f;
    }
    acc += bf2f(xb[i * 128 + f]);
  }
  if (cur >= 0) atomicAdd(&pooled[cur * 128 + f], acc);
}

// h1 = relu(pooled @ fc1_W^T + b)   [128,128] fp32
__global__ void fc1_kernel(const float* __restrict__ pooled, const float* __restrict__ W,
                           const float* __restrict__ b, float* __restrict__ out) {
  int idx = blockIdx.x * 256 + threadIdx.x;
  if (idx >= NG * 128) return;
  int r = idx >> 7, c = idx & 127;
  float acc = 0.f;
  for (int k = 0; k < 128; ++k) acc += pooled[r * 128 + k] * W[c * 128 + k];
  acc += b[c];
  out[idx] = acc > 0.f ? acc : 0.f;
}

// out = h1 @ fc2_W^T + b   [128,41] fp32
__global__ void fc2_kernel(const float* __restrict__ h1, const float* __restrict__ W,
                           const float* __restrict__ b, float* __restrict__ out) {
  int idx = blockIdx.x * 256 + threadIdx.x;
  if (idx >= NG * NC) return;
  int r = idx / NC, c = idx % NC;
  float acc = 0.f;
  for (int k = 0; k < 128; ++k) acc += h1[r * 128 + k] * W[c * 128 + k];
  out[idx] = acc + b[c];
}

extern "C" void kernel_launch(void* const* d_in, const int* in_sizes, int n_in,
                              void* d_out, int out_size, void* d_ws, size_t ws_size,
                              hipStream_t stream) {
  const int* node_ids = (const int*)d_in[0];
  const int* edge_index = (const int*)d_in[1];
  const int* batch = (const int*)d_in[2];
  const float* emb = (const float*)d_in[3];
  const float* in_W1 = (const float*)d_in[4];
  const float* in_b1 = (const float*)d_in[5];
  const float* in_W2 = (const float*)d_in[6];
  const float* in_b2 = (const float*)d_in[7];
  const float* bn_gamma = (const float*)d_in[8];
  const float* bn_beta = (const float*)d_in[9];
  const float* bn_mean = (const float*)d_in[10];
  const float* bn_var = (const float*)d_in[11];
  const float* out_W1 = (const float*)d_in[12];
  const float* out_b1 = (const float*)d_in[13];
  const float* out_W2 = (const float*)d_in[14];
  const float* out_b2 = (const float*)d_in[15];
  const float* fc1_W = (const float*)d_in[16];
  const float* fc1_b = (const float*)d_in[17];
  const float* fc2_W = (const float*)d_in[18];
  const float* fc2_b = (const float*)d_in[19];
  float* out = (float*)d_out;

  char* ws = (char*)d_ws;
  size_t off = 0;
  auto alloc = [&](size_t bytes) {
    char* p = ws + off;
    off = (off + bytes + 255) & ~(size_t)255;
    return p;
  };
  unsigned short* xb = (unsigned short*)alloc((size_t)NN * 128 * 2);
  unsigned short* hb = (unsigned short*)alloc((size_t)NN * 128 * 2);
  int* srclist = (int*)alloc((size_t)NN * CAP * 4);
  int* cnt = (int*)alloc((size_t)NN * 4);
  unsigned short* W1b = (unsigned short*)alloc(128 * 128 * 2);
  unsigned short* W2b = (unsigned short*)alloc(128 * 128 * 2);
  unsigned short* oW1b = (unsigned short*)alloc(128 * 128 * 2);
  unsigned short* oW2b = (unsigned short*)alloc(128 * 128 * 2);
  float* bnscale = (float*)alloc(128 * 4);
  float* bnshift = (float*)alloc(128 * 4);
  float* pooled = (float*)alloc(NG * 128 * 4);
  float* h1 = (float*)alloc(NG * 128 * 4);

  hipMemsetAsync(cnt, 0, (size_t)NN * 4, stream);
  hipMemsetAsync(pooled, 0, (size_t)NG * 128 * 4, stream);

  pre_kernel<<<9439, 256, 0, stream>>>(node_ids, emb, xb, edge_index, cnt, srclist,
                                       in_W1, in_W2, out_W1, out_W2,
                                       bn_gamma, bn_beta, bn_mean, bn_var,
                                       W1b, W2b, oW1b, oW2b, bnscale, bnshift);

  int mlp_blocks = (NN + 63) / 64;
  for (int l = 0; l < 6; ++l) {
    const unsigned short* w1 = (l < 5) ? W1b : oW1b;
    const unsigned short* w2 = (l < 5) ? W2b : oW2b;
    const float* b1 = (l < 5) ? in_b1 : out_b1;
    const float* b2 = (l < 5) ? in_b2 : out_b2;
    int mode2 = (l < 5) ? 1 : 0;
    agg_kernel<<<(NN + 15) / 16, 256, 0, stream>>>(xb, cnt, srclist, hb);
    mlp_kernel<<<mlp_blocks, 256, 0, stream>>>(hb, w1, w2, b1, b2, bnscale, bnshift,
                                               xb, NN, mode2);
  }

  pool_kernel<<<(NN + 127) / 128, 128, 0, stream>>>(xb, batch, pooled);
  fc1_kernel<<<(NG * 128 + 255) / 256, 256, 0, stream>>>(pooled, fc1_W, fc1_b, h1);
  fc2_kernel<<<(NG * NC + 255) / 256, 256, 0, stream>>>(h1, fc2_W, fc2_b, out);
}

// Round 5
// 497.834 us; speedup vs baseline: 1.1032x; 1.1032x over previous
//
#include <hip/hip_runtime.h>

#define NN 50000
#define NE 800000
#define NG 128
#define NC 41
#define CAP 64

typedef __attribute__((ext_vector_type(8))) short bfrag8;
typedef __attribute__((ext_vector_type(4))) float facc4;

__device__ __forceinline__ float bf2f(unsigned short u) {
  union { unsigned int i; float f; } v; v.i = ((unsigned int)u) << 16; return v.f;
}
__device__ __forceinline__ unsigned short f2bf(float f) {
  union { float f; unsigned int i; } v; v.f = f;
  unsigned int x = v.i;
  x += 0x7fffu + ((x >> 16) & 1u);
  return (unsigned short)(x >> 16);
}
__device__ __forceinline__ void acc_u4(const uint4 u, float* a) {
  union { unsigned int i; float f; } c;
  c.i = u.x << 16;          a[0] += c.f;
  c.i = u.x & 0xffff0000u;  a[1] += c.f;
  c.i = u.y << 16;          a[2] += c.f;
  c.i = u.y & 0xffff0000u;  a[3] += c.f;
  c.i = u.z << 16;          a[4] += c.f;
  c.i = u.z & 0xffff0000u;  a[5] += c.f;
  c.i = u.w << 16;          a[6] += c.f;
  c.i = u.w & 0xffff0000u;  a[7] += c.f;
}
__device__ __forceinline__ unsigned int pack2(float lo, float hi) {
  return (unsigned int)f2bf(lo) | ((unsigned int)f2bf(hi) << 16);
}

// Weights -> bf16, BN affine precompute (applied AFTER relu).
__global__ void prep_kernel(const float* __restrict__ W1, const float* __restrict__ W2,
                            const float* __restrict__ oW1, const float* __restrict__ oW2,
                            const float* __restrict__ gamma, const float* __restrict__ beta,
                            const float* __restrict__ mean, const float* __restrict__ var,
                            unsigned short* W1b, unsigned short* W2b,
                            unsigned short* oW1b, unsigned short* oW2b,
                            float* scale, float* shift) {
  int i = blockIdx.x * 256 + threadIdx.x;
  if (i < 128 * 128) {
    W1b[i] = f2bf(W1[i]);
    W2b[i] = f2bf(W2[i]);
    oW1b[i] = f2bf(oW1[i]);
    oW2b[i] = f2bf(oW2[i]);
  }
  if (i < 128) {
    float s = gamma[i] * rsqrtf(var[i] + 1e-5f);
    scale[i] = s;
    shift[i] = beta[i] - mean[i] * s;
  }
}

// x = emb[node_ids], stored bf16. One thread per 4 feats.
__global__ void embed_kernel(const int* __restrict__ node_ids, const float* __restrict__ emb,
                             unsigned short* __restrict__ xb) {
  int idx = blockIdx.x * 256 + threadIdx.x;
  if (idx >= NN * 32) return;
  int node = idx >> 5, f = (idx & 31) * 4;
  const float4 v = *(const float4*)&emb[node_ids[node] * 128 + f];
  ushort4 o;
  o.x = f2bf(v.x); o.y = f2bf(v.y); o.z = f2bf(v.z); o.w = f2bf(v.w);
  *(ushort4*)&xb[node * 128 + f] = o;
}

// bucket edges by dst: srclist[dst*CAP + pos] = src
__global__ void fill_kernel(const int* __restrict__ ei, int* __restrict__ cnt,
                            int* __restrict__ srclist) {
  int e = blockIdx.x * 256 + threadIdx.x;
  if (e >= NE) return;
  int s = ei[e];
  int d = ei[NE + e];
  int pos = atomicAdd(&cnt[d], 1);
  if (pos < CAP) srclist[d * CAP + pos] = s;
}

// h = x + sum_{neighbors} x. 16 nodes/block, 16 lanes/node, 16B loads, unroll 8/4/1.
__global__ __launch_bounds__(256) void agg_kernel(const unsigned short* __restrict__ xb,
                                                  const int* __restrict__ cnt,
                                                  const int* __restrict__ srclist,
                                                  unsigned short* __restrict__ hb) {
  int tid = threadIdx.x;
  int node = blockIdx.x * 16 + (tid >> 4);
  if (node >= NN) return;
  int f = (tid & 15) * 8;
  float a[8];
  acc_u4(*(const uint4*)&xb[node * 128 + f],
         (a[0]=0.f, a[1]=0.f, a[2]=0.f, a[3]=0.f, a[4]=0.f, a[5]=0.f, a[6]=0.f, a[7]=0.f, a));
  int deg = cnt[node];
  if (deg > CAP) deg = CAP;
  const int* lst = &srclist[node * CAP];
  int j = 0;
  for (; j + 8 <= deg; j += 8) {
    uint4 u0 = *(const uint4*)&xb[lst[j] * 128 + f];
    uint4 u1 = *(const uint4*)&xb[lst[j + 1] * 128 + f];
    uint4 u2 = *(const uint4*)&xb[lst[j + 2] * 128 + f];
    uint4 u3 = *(const uint4*)&xb[lst[j + 3] * 128 + f];
    uint4 u4 = *(const uint4*)&xb[lst[j + 4] * 128 + f];
    uint4 u5 = *(const uint4*)&xb[lst[j + 5] * 128 + f];
    uint4 u6 = *(const uint4*)&xb[lst[j + 6] * 128 + f];
    uint4 u7 = *(const uint4*)&xb[lst[j + 7] * 128 + f];
    acc_u4(u0, a); acc_u4(u1, a); acc_u4(u2, a); acc_u4(u3, a);
    acc_u4(u4, a); acc_u4(u5, a); acc_u4(u6, a); acc_u4(u7, a);
  }
  for (; j + 4 <= deg; j += 4) {
    uint4 u0 = *(const uint4*)&xb[lst[j] * 128 + f];
    uint4 u1 = *(const uint4*)&xb[lst[j + 1] * 128 + f];
    uint4 u2 = *(const uint4*)&xb[lst[j + 2] * 128 + f];
    uint4 u3 = *(const uint4*)&xb[lst[j + 3] * 128 + f];
    acc_u4(u0, a); acc_u4(u1, a); acc_u4(u2, a); acc_u4(u3, a);
  }
  for (; j < deg; ++j) {
    uint4 u = *(const uint4*)&xb[lst[j] * 128 + f];
    acc_u4(u, a);
  }
  uint4 o;
  o.x = pack2(a[0], a[1]); o.y = pack2(a[2], a[3]);
  o.z = pack2(a[4], a[5]); o.w = pack2(a[6], a[7]);
  *(uint4*)&hb[node * 128 + f] = o;
}

// Fused MLP: Out = ep2(relu(A@W1^T+b1) @ W2^T + b2) for a 128-row tile.
// 512 threads (8 waves), 139KB LDS -> 1 block/CU, 8 waves/CU.
// Barriers between all LDS producer/consumer phases (round-2 proven structure).
__global__ __launch_bounds__(512) void mlp_kernel(const unsigned short* __restrict__ A,
                                                  const unsigned short* __restrict__ W1b,
                                                  const unsigned short* __restrict__ W2b,
                                                  const float* __restrict__ bias1,
                                                  const float* __restrict__ bias2,
                                                  const float* __restrict__ scale,
                                                  const float* __restrict__ shift,
                                                  unsigned short* __restrict__ Out,
                                                  int M, int mode) {
  __shared__ unsigned short sW1[128][136];
  __shared__ unsigned short sW2[128][136];
  __shared__ unsigned short sA[128][136];
  __shared__ unsigned short sT[128][136];
  int tid = threadIdx.x;
  int bRow = blockIdx.x * 128;

  const uint4* gw1 = (const uint4*)W1b;
  const uint4* gw2 = (const uint4*)W2b;
#pragma unroll
  for (int p = 0; p < 4; ++p) {
    int idx = (p * 512 + tid) * 8;
    int r = idx >> 7, c = idx & 127;
    *(uint4*)&sW1[r][c] = gw1[p * 512 + tid];
    *(uint4*)&sW2[r][c] = gw2[p * 512 + tid];
  }
#pragma unroll
  for (int p = 0; p < 4; ++p) {
    int idx = (p * 512 + tid) * 8;
    int r = idx >> 7, c = idx & 127;
    int grow = bRow + r;
    uint4 v = {0u, 0u, 0u, 0u};
    if (grow < M) v = *(const uint4*)&A[grow * 128 + c];
    *(uint4*)&sA[r][c] = v;
  }
  __syncthreads();

  int wave = tid >> 6;   // 0..7
  int lane = tid & 63;
  int l16 = lane & 15;
  int quad = lane >> 4;
  int arow = wave * 16 + l16;   // 0..127

  // ---- GEMM1: T = relu(A @ W1^T + b1) ----
  {
    facc4 acc[8];
#pragma unroll
    for (int t = 0; t < 8; ++t) acc[t] = (facc4){0.f, 0.f, 0.f, 0.f};
#pragma unroll
    for (int k = 0; k < 4; ++k) {
      bfrag8 af = *(const bfrag8*)&sA[arow][k * 32 + quad * 8];
#pragma unroll
      for (int t = 0; t < 8; ++t) {
        bfrag8 bf = *(const bfrag8*)&sW1[t * 16 + l16][k * 32 + quad * 8];
        acc[t] = __builtin_amdgcn_mfma_f32_16x16x32_bf16(af, bf, acc[t], 0, 0, 0);
      }
    }
#pragma unroll
    for (int t = 0; t < 8; ++t) {
      int col = t * 16 + l16;
      float b = bias1[col];
#pragma unroll
      for (int i = 0; i < 4; ++i) {
        int row = wave * 16 + quad * 4 + i;
        float v = acc[t][i] + b;
        sT[row][col] = f2bf(v > 0.f ? v : 0.f);
      }
    }
  }
  __syncthreads();

  // ---- GEMM2: Out = ep2(T @ W2^T + b2) ----
  {
    facc4 acc[8];
#pragma unroll
    for (int t = 0; t < 8; ++t) acc[t] = (facc4){0.f, 0.f, 0.f, 0.f};
#pragma unroll
    for (int k = 0; k < 4; ++k) {
      bfrag8 af = *(const bfrag8*)&sT[arow][k * 32 + quad * 8];
#pragma unroll
      for (int t = 0; t < 8; ++t) {
        bfrag8 bf = *(const bfrag8*)&sW2[t * 16 + l16][k * 32 + quad * 8];
        acc[t] = __builtin_amdgcn_mfma_f32_16x16x32_bf16(af, bf, acc[t], 0, 0, 0);
      }
    }
#pragma unroll
    for (int t = 0; t < 8; ++t) {
      int col = t * 16 + l16;
      float b = bias2[col];
      float sc = 1.f, sh = 0.f;
      if (mode == 1) { sc = scale[col]; sh = shift[col]; }
#pragma unroll
      for (int i = 0; i < 4; ++i) {
        int row = wave * 16 + quad * 4 + i;
        float v = acc[t][i] + b;
        v = v > 0.f ? v : 0.f;
        if (mode == 1) v = v * sc + sh;
        sA[row][col] = f2bf(v);
      }
    }
  }
  __syncthreads();

#pragma unroll
  for (int p = 0; p < 4; ++p) {
    int idx = (p * 512 + tid) * 8;
    int r = idx >> 7, c = idx & 127;
    int grow = bRow + r;
    if (grow < M) *(uint4*)&Out[grow * 128 + c] = *(const uint4*)&sA[r][c];
  }
}

// pooled[g, f] += sum over contiguous nodes with batch==g (batch sorted)
__global__ __launch_bounds__(128) void pool_kernel(const unsigned short* __restrict__ xb,
                                                   const int* __restrict__ batch,
                                                   float* __restrict__ pooled) {
  const int CHUNK = 128;
  int start = blockIdx.x * CHUNK;
  int end = start + CHUNK;
  if (end > NN) end = NN;
  int f = threadIdx.x;
  float acc = 0.f;
  int cur = -1;
  for (int i = start; i < end; ++i) {
    int b = batch[i];
    if (b != cur) {
      if (cur >= 0) atomicAdd(&pooled[cur * 128 + f], acc);
      cur = b;
      acc = 0.f;
    }
    acc += bf2f(xb[i * 128 + f]);
  }
  if (cur >= 0) atomicAdd(&pooled[cur * 128 + f], acc);
}

// h1 = relu(pooled @ fc1_W^T + b)   [128,128] fp32
__global__ void fc1_kernel(const float* __restrict__ pooled, const float* __restrict__ W,
                           const float* __restrict__ b, float* __restrict__ out) {
  int idx = blockIdx.x * 256 + threadIdx.x;
  if (idx >= NG * 128) return;
  int r = idx >> 7, c = idx & 127;
  float acc = 0.f;
  for (int k = 0; k < 128; ++k) acc += pooled[r * 128 + k] * W[c * 128 + k];
  acc += b[c];
  out[idx] = acc > 0.f ? acc : 0.f;
}

// out = h1 @ fc2_W^T + b   [128,41] fp32
__global__ void fc2_kernel(const float* __restrict__ h1, const float* __restrict__ W,
                           const float* __restrict__ b, float* __restrict__ out) {
  int idx = blockIdx.x * 256 + threadIdx.x;
  if (idx >= NG * NC) return;
  int r = idx / NC, c = idx % NC;
  float acc = 0.f;
  for (int k = 0; k < 128; ++k) acc += h1[r * 128 + k] * W[c * 128 + k];
  out[idx] = acc + b[c];
}

extern "C" void kernel_launch(void* const* d_in, const int* in_sizes, int n_in,
                              void* d_out, int out_size, void* d_ws, size_t ws_size,
                              hipStream_t stream) {
  const int* node_ids = (const int*)d_in[0];
  const int* edge_index = (const int*)d_in[1];
  const int* batch = (const int*)d_in[2];
  const float* emb = (const float*)d_in[3];
  const float* in_W1 = (const float*)d_in[4];
  const float* in_b1 = (const float*)d_in[5];
  const float* in_W2 = (const float*)d_in[6];
  const float* in_b2 = (const float*)d_in[7];
  const float* bn_gamma = (const float*)d_in[8];
  const float* bn_beta = (const float*)d_in[9];
  const float* bn_mean = (const float*)d_in[10];
  const float* bn_var = (const float*)d_in[11];
  const float* out_W1 = (const float*)d_in[12];
  const float* out_b1 = (const float*)d_in[13];
  const float* out_W2 = (const float*)d_in[14];
  const float* out_b2 = (const float*)d_in[15];
  const float* fc1_W = (const float*)d_in[16];
  const float* fc1_b = (const float*)d_in[17];
  const float* fc2_W = (const float*)d_in[18];
  const float* fc2_b = (const float*)d_in[19];
  float* out = (float*)d_out;

  char* ws = (char*)d_ws;
  size_t off = 0;
  auto alloc = [&](size_t bytes) {
    char* p = ws + off;
    off = (off + bytes + 255) & ~(size_t)255;
    return p;
  };
  unsigned short* xb = (unsigned short*)alloc((size_t)NN * 128 * 2);
  unsigned short* hb = (unsigned short*)alloc((size_t)NN * 128 * 2);
  int* srclist = (int*)alloc((size_t)NN * CAP * 4);
  int* cnt = (int*)alloc((size_t)NN * 4);
  unsigned short* W1b = (unsigned short*)alloc(128 * 128 * 2);
  unsigned short* W2b = (unsigned short*)alloc(128 * 128 * 2);
  unsigned short* oW1b = (unsigned short*)alloc(128 * 128 * 2);
  unsigned short* oW2b = (unsigned short*)alloc(128 * 128 * 2);
  float* bnscale = (float*)alloc(128 * 4);
  float* bnshift = (float*)alloc(128 * 4);
  float* pooled = (float*)alloc(NG * 128 * 4);
  float* h1 = (float*)alloc(NG * 128 * 4);

  hipMemsetAsync(cnt, 0, (size_t)NN * 4, stream);
  hipMemsetAsync(pooled, 0, (size_t)NG * 128 * 4, stream);

  prep_kernel<<<64, 256, 0, stream>>>(in_W1, in_W2, out_W1, out_W2,
                                      bn_gamma, bn_beta, bn_mean, bn_var,
                                      W1b, W2b, oW1b, oW2b, bnscale, bnshift);
  fill_kernel<<<(NE + 255) / 256, 256, 0, stream>>>(edge_index, cnt, srclist);
  embed_kernel<<<(NN * 32 + 255) / 256, 256, 0, stream>>>(node_ids, emb, xb);

  int mlp_blocks = (NN + 127) / 128;
  for (int l = 0; l < 6; ++l) {
    const unsigned short* w1 = (l < 5) ? W1b : oW1b;
    const unsigned short* w2 = (l < 5) ? W2b : oW2b;
    const float* b1 = (l < 5) ? in_b1 : out_b1;
    const float* b2 = (l < 5) ? in_b2 : out_b2;
    int mode2 = (l < 5) ? 1 : 0;
    agg_kernel<<<(NN + 15) / 16, 256, 0, stream>>>(xb, cnt, srclist, hb);
    mlp_kernel<<<mlp_blocks, 512, 0, stream>>>(hb, w1, w2, b1, b2, bnscale, bnshift,
                                               xb, NN, mode2);
  }

  pool_kernel<<<(NN + 127) / 128, 128, 0, stream>>>(xb, batch, pooled);
  fc1_kernel<<<(NG * 128 + 255) / 256, 256, 0, stream>>>(pooled, fc1_W, fc1_b, h1);
  fc2_kernel<<<(NG * NC + 255) / 256, 256, 0, stream>>>(h1, fc2_W, fc2_b, out);
}